// Round 15
// baseline (1372.027 us; speedup 1.0000x reference)
//
#include <hip/hip_runtime.h>

#define NN 100000
#define NE 3200000
#define NB 98   // ceil(NN/1024)

typedef unsigned int u32;
typedef unsigned short u16;
typedef _Float16 f16x2 __attribute__((ext_vector_type(2)));
typedef __fp16 fp16v2 __attribute__((ext_vector_type(2)));

__device__ __forceinline__ int clampi(int s){
  s = s < 0 ? 0 : s;
  return s >= NN ? NN-1 : s;
}

__device__ __forceinline__ f16x2 pk2(float x, float y){
  fp16v2 r = __builtin_amdgcn_cvt_pkrtz(x, y);
  return __builtin_bit_cast(f16x2, r);
}
__device__ __forceinline__ float dot2(f16x2 a, f16x2 b, float c){
  return __builtin_amdgcn_fdot2(a, b, c, false);
}
__device__ __forceinline__ float f16lo(u32 w){
  __fp16 h = __builtin_bit_cast(__fp16, (u16)(w & 0xffffu));
  return (float)h;
}
__device__ __forceinline__ float f16hi(u32 w){
  __fp16 h = __builtin_bit_cast(__fp16, (u16)(w >> 16));
  return (float)h;
}
__device__ __forceinline__ float f16u(u16 w){
  __fp16 h = __builtin_bit_cast(__fp16, w);
  return (float)h;
}

// dual-accumulator dot (f32, used by k4)
template<int N4>
__device__ __forceinline__ float dotl(const float* __restrict__ a, const float* w){
  float acc0 = 0.f, acc1 = 0.f;
  #pragma unroll
  for (int k = 0; k < N4; k += 2){
    float4 q0 = ((const float4*)w)[k];
    acc0 += a[4*k]*q0.x + a[4*k+1]*q0.y + a[4*k+2]*q0.z + a[4*k+3]*q0.w;
    float4 q1 = ((const float4*)w)[k+1];
    acc1 += a[4*k+4]*q1.x + a[4*k+5]*q1.y + a[4*k+6]*q1.z + a[4*k+7]*q1.w;
  }
  return acc0 + acc1;
}

// ---------------- khist: cnt[d]++ ------------------------------------------
__global__ __launch_bounds__(256,8) void khist(const int* __restrict__ ei, int* __restrict__ cnt){
  int i = blockIdx.x*256 + threadIdx.x;
  if (i >= NE) return;
  atomicAdd(&cnt[clampi(ei[NE+i])], 1);
}

// ---------------- kscanA: per-block sums of cnt -----------------------------
__global__ __launch_bounds__(1024) void kscanA(const int* __restrict__ cnt, int* __restrict__ bsum){
  __shared__ int wsum[16];
  int tid = threadIdx.x;
  int i = blockIdx.x*1024 + tid;
  int x = (i < NN) ? cnt[i] : 0;
  #pragma unroll
  for (int ofs = 1; ofs < 64; ofs <<= 1) x += __shfl_xor(x, ofs, 64);
  if ((tid & 63) == 0) wsum[tid >> 6] = x;
  __syncthreads();
  if (tid == 0){
    int t = 0;
    #pragma unroll
    for (int k = 0; k < 16; k++) t += wsum[k];
    bsum[blockIdx.x] = t;
  }
}

// ---------------- kscanB: scan the 98 block sums ----------------------------
__global__ void kscanB(const int* __restrict__ bsum, int* __restrict__ boff, int* __restrict__ offN){
  if (threadIdx.x == 0){
    int c = 0;
    for (int b = 0; b < NB; b++){ boff[b] = c; c += bsum[b]; }
    offN[0] = c;
  }
}

// ---------------- kscanC: block scan + offset; cnt=0; zero acc4,s -----------
__global__ __launch_bounds__(1024) void kscanC(int* __restrict__ cnt, const int* __restrict__ boff,
                                               int* __restrict__ off,
                                               float* __restrict__ acc4, float* __restrict__ s){
  __shared__ int wsum[16];
  int tid = threadIdx.x;
  int i = blockIdx.x*1024 + tid;
  int v = (i < NN) ? cnt[i] : 0;
  int x = v;
  #pragma unroll
  for (int ofs = 1; ofs < 64; ofs <<= 1){
    int t = __shfl_up(x, ofs, 64);
    if ((tid & 63) >= ofs) x += t;
  }
  if ((tid & 63) == 63) wsum[tid >> 6] = x;
  __syncthreads();
  if (tid < 16){
    int y = wsum[tid];
    #pragma unroll
    for (int ofs = 1; ofs < 16; ofs <<= 1){
      int t = __shfl_up(y, ofs, 64);
      if (tid >= ofs) y += t;
    }
    wsum[tid] = y;
  }
  __syncthreads();
  int wb = (tid >= 64) ? wsum[(tid >> 6) - 1] : 0;
  if (i < NN){
    off[i] = boff[blockIdx.x] + wb + x - v;
    cnt[i] = 0;
    s[i] = 0.f;
    float4 z; z.x=z.y=z.z=z.w=0.f;
    ((float4*)acc4)[i] = z;
  }
}

// ---------------- k1: hs1 = (Wx x).a_src ; hd1 = (Wx x).a_dst ---------------
__global__ __launch_bounds__(256,4) void k1(const float* __restrict__ x,
    const float* __restrict__ Wx, const float* __restrict__ asrc, const float* __restrict__ adst,
    float* __restrict__ hs1, float* __restrict__ hd1)
{
  __shared__ float wL[64], aS[16], aD[16];
  int tid = threadIdx.x;
  if (tid < 64) wL[tid] = Wx[tid];
  if (tid < 16){ aS[tid] = asrc[tid]; aD[tid] = adst[tid]; }
  __syncthreads();
  int n = blockIdx.x*256 + tid;
  if (n >= NN) return;
  float4 xr = ((const float4*)x)[n];
  float hs=0.f, hd=0.f;
  #pragma unroll
  for (int j=0;j<16;j++){
    float h = xr.x*wL[j*4+0] + xr.y*wL[j*4+1] + xr.z*wL[j*4+2] + xr.w*wL[j*4+3];
    hs += h*aS[j]; hd += h*aD[j];
  }
  hs1[n]=hs; hd1[n]=hd;
}

// ---------------- k2a: alpha1 -> 5 atomics into L2-resident acc4/s ----------
// conv1 aggregates 4-dim x (linearity through Wx), so no CSR pass needed:
// acc4 (1.6MB) + s (0.4MB) are L2-resident; 5 f32 atomics/edge.
__global__ __launch_bounds__(256,8) void k2a(const int* __restrict__ ei,
    const float* __restrict__ ea, const float* __restrict__ We, const float* __restrict__ aedge,
    const float* __restrict__ hs1, const float* __restrict__ hd1,
    const float* __restrict__ x,
    float* __restrict__ acc4, float* __restrict__ s1)
{
  __shared__ float w6[6];
  int tid = threadIdx.x;
  if (tid < 6){
    float acc = 0.f;
    for (int j=0;j<16;j++) acc += aedge[j] * We[j*6+tid];
    w6[tid] = acc;
  }
  __syncthreads();
  int i = blockIdx.x*256 + tid;
  if (i >= NE) return;
  int s = clampi(ei[i]);
  int d = clampi(ei[NE + i]);
  const float2* eap = (const float2*)ea + (size_t)i*3;
  float2 u0 = eap[0], u1 = eap[1], u2 = eap[2];
  float al = hs1[s] + hd1[d]
    + u0.x*w6[0] + u0.y*w6[1] + u1.x*w6[2]
    + u1.y*w6[3] + u2.x*w6[4] + u2.y*w6[5];
  al = al > 0.f ? al : 0.2f*al;
  float ex = __expf(al);
  float4 xs = ((const float4*)x)[s];
  unsafeAtomicAdd(&s1[d], ex);
  float* a4 = acc4 + (size_t)d*4;
  unsafeAtomicAdd(a4+0, ex*xs.x);
  unsafeAtomicAdd(a4+1, ex*xs.y);
  unsafeAtomicAdd(a4+2, ex*xs.z);
  unsafeAtomicAdd(a4+3, ex*xs.w);
}

// ---------------- k4: x1 = Wx1.(acc4/s) + b1 ; h2 ; hs2 ; hd2 ; u,v ---------
__global__ __launch_bounds__(256,2) void k4(const float* __restrict__ acc4,
    const float* __restrict__ sb, const float* __restrict__ c1b,
    const float* __restrict__ Wx1, const float* __restrict__ Wx2,
    const float* __restrict__ a2s, const float* __restrict__ a2d,
    const float* __restrict__ w1p,
    u32* __restrict__ hpk,
    float* __restrict__ hs2, float* __restrict__ hd2,
    u32* __restrict__ uh, u32* __restrict__ vh)
{
  __shared__ float wL[256], bL[16], aS[16], aD[16], w0L[64];
  __shared__ float w1sL[32*16], w1dL[32*16];
  int tid = threadIdx.x;
  wL[tid] = Wx2[tid];
  if (tid < 64) w0L[tid] = Wx1[tid];
  if (tid < 16){ bL[tid]=c1b[tid]; aS[tid]=a2s[tid]; aD[tid]=a2d[tid]; }
  for (int idx=tid; idx<512; idx+=256){
    int j=idx>>4, k=idx&15;
    w1sL[idx] = w1p[j*38+k];
    w1dL[idx] = w1p[j*38+22+k];
  }
  __syncthreads();
  int n = blockIdx.x*256 + tid;
  if (n >= NN) return;
  float inv = 1.f/(sb[n] + 1e-16f);
  float4 a4 = ((const float4*)acc4)[n];
  float m0 = a4.x*inv, m1 = a4.y*inv, m2 = a4.z*inv, m3 = a4.w*inv;
  float xv[16];
  #pragma unroll
  for (int j=0;j<16;j++)
    xv[j] = m0*w0L[j*4+0] + m1*w0L[j*4+1] + m2*w0L[j*4+2] + m3*w0L[j*4+3] + bL[j];
  float hs=0.f, hd=0.f;
  float hv[16];
  #pragma unroll
  for (int j=0;j<16;j++){
    float acc = 0.f;
    #pragma unroll
    for (int k=0;k<16;k++) acc += xv[k]*wL[j*16+k];
    hv[j] = acc; hs += acc*aS[j]; hd += acc*aD[j];
  }
  u32* hr = hpk + (size_t)n*8;
  #pragma unroll
  for (int j=0;j<8;j++) hr[j] = __builtin_bit_cast(u32, pk2(hv[2*j], hv[2*j+1]));
  hs2[n]=hs; hd2[n]=hd;
  u32* ur = uh + (size_t)n*16;
  u32* vr = vh + (size_t)n*16;
  #pragma unroll
  for (int j=0;j<16;j++){
    float u0 = dotl<4>(xv, &w1sL[(2*j)*16]);
    float u1 = dotl<4>(xv, &w1sL[(2*j+1)*16]);
    ur[j] = __builtin_bit_cast(u32, pk2(u0, u1));
    float v0 = dotl<4>(xv, &w1dL[(2*j)*16]);
    float v1 = dotl<4>(xv, &w1dL[(2*j+1)*16]);
    vr[j] = __builtin_bit_cast(u32, pk2(v0, v1));
  }
}

// ---------------- k5: edge MLP (f16 dot2) + edge head + alpha2 scatter ------
// (256,5): known-good from r13/r14 (370us, VGPR 48, no spill). UNCHANGED.
__global__ __launch_bounds__(256,5) void k5(
    const int* __restrict__ ei, const float* __restrict__ ea,
    const u32* __restrict__ uh, const u32* __restrict__ vh,
    const float* __restrict__ hs2, const float* __restrict__ hd2,
    const float* w1p, const float* b1p, const float* w2p, const float* b2p,
    const float* w3p, const float* b3p, const float* w4p, const float* b4p,
    const float* We2, const float* a2e,
    const float* ew1p, const float* eb1p, const float* ew2p, const float* eb2p,
    const int* __restrict__ off, int* __restrict__ cnt, float2* __restrict__ edata,
    float* __restrict__ eout)
{
  __shared__ __align__(16) f16x2 w1eh[32*4];  __shared__ float b1L[32];
  __shared__ __align__(16) f16x2 w2h[64*16];  __shared__ float b2L[64];
  __shared__ __align__(16) f16x2 w3h[32*32];  __shared__ float b3L[32];
  __shared__ __align__(16) f16x2 w4h[16*16];  __shared__ float b4L[16];
  __shared__ __align__(16) f16x2 ew1h[16*8];  __shared__ float eb1L[16];
  __shared__ __align__(16) f16x2 ew2h[4*8];   __shared__ float eb2L[4];
  __shared__ __align__(16) f16x2 w16h[8];
  int tid = threadIdx.x;
  if (tid < 128){
    int j=tid>>2, kk=tid&3;
    int k0=2*kk, k1=2*kk+1;
    float v0 = (k0<6) ? w1p[j*38+16+k0] : 0.f;
    float v1 = (k1<6) ? w1p[j*38+16+k1] : 0.f;
    w1eh[tid] = pk2(v0, v1);
  }
  for (int idx=tid; idx<1024; idx+=256){
    int j=idx>>4, kk=idx&15;
    w2h[idx] = pk2(w2p[j*32+2*kk], w2p[j*32+2*kk+1]);
  }
  for (int idx=tid; idx<1024; idx+=256){
    int j=idx>>5, kk=idx&31;
    w3h[idx] = pk2(w3p[j*64+2*kk], w3p[j*64+2*kk+1]);
  }
  if (tid < 256){
    int j=tid>>4, kk=tid&15;
    w4h[tid] = pk2(w4p[j*32+2*kk], w4p[j*32+2*kk+1]);
  }
  if (tid < 128){
    int j=tid>>3, kk=tid&7;
    ew1h[tid] = pk2(ew1p[j*16+2*kk], ew1p[j*16+2*kk+1]);
  }
  if (tid < 32){
    int j=tid>>3, kk=tid&7;
    ew2h[tid] = pk2(ew2p[j*16+2*kk], ew2p[j*16+2*kk+1]);
  }
  if (tid < 8){
    float s0=0.f, s1=0.f;
    for (int j=0;j<16;j++){
      s0 += a2e[j] * We2[j*16 + 2*tid];
      s1 += a2e[j] * We2[j*16 + 2*tid + 1];
    }
    w16h[tid] = pk2(s0, s1);
  }
  if (tid < 64) b2L[tid] = b2p[tid];
  if (tid < 32){ b1L[tid] = b1p[tid]; b3L[tid] = b3p[tid]; }
  if (tid < 16){ b4L[tid] = b4p[tid]; eb1L[tid] = eb1p[tid]; }
  if (tid < 4)  eb2L[tid] = eb2p[tid];
  __syncthreads();

  int i = blockIdx.x*256 + tid;
  if (i >= NE) return;
  int s = clampi(ei[i]);
  int d = clampi(ei[NE + i]);

  // ---- layer 1: a1 = relu(u[s] + v[d] + W1e.ea + b1) ----
  f16x2 a1h[16];
  {
    const float2* eap = (const float2*)ea + (size_t)i*3;
    float2 e0=eap[0], e1=eap[1], e2=eap[2];
    f16x2 eh[4];
    eh[0]=pk2(e0.x,e0.y); eh[1]=pk2(e1.x,e1.y); eh[2]=pk2(e2.x,e2.y); eh[3]=pk2(0.f,0.f);
    const uint4* up = (const uint4*)(uh + (size_t)s*16);
    const uint4* vp = (const uint4*)(vh + (size_t)d*16);
    uint4 U[4], V[4];
    #pragma unroll
    for (int q=0;q<4;q++){ U[q]=up[q]; V[q]=vp[q]; }
    u32 uw[16], vw[16];
    #pragma unroll
    for (int q=0;q<4;q++){
      uw[4*q]=U[q].x; uw[4*q+1]=U[q].y; uw[4*q+2]=U[q].z; uw[4*q+3]=U[q].w;
      vw[4*q]=V[q].x; vw[4*q+1]=V[q].y; vw[4*q+2]=V[q].z; vw[4*q+3]=V[q].w;
    }
    #pragma unroll
    for (int j=0;j<16;j++){
      float t0 = b1L[2*j]   + f16lo(uw[j]) + f16lo(vw[j]);
      float t1 = b1L[2*j+1] + f16hi(uw[j]) + f16hi(vw[j]);
      #pragma unroll
      for (int kk=0;kk<4;kk++){
        t0 = dot2(eh[kk], w1eh[(2*j)*4+kk],   t0);
        t1 = dot2(eh[kk], w1eh[(2*j+1)*4+kk], t1);
      }
      a1h[j] = pk2(fmaxf(t0,0.f), fmaxf(t1,0.f));
    }
  }
  // ---- layer 2: 32 -> 64 ----
  f16x2 a2h[32];
  #pragma unroll
  for (int j=0;j<32;j++){
    float acc0 = b2L[2*j], acc1 = b2L[2*j+1];
    #pragma unroll
    for (int kk=0;kk<16;kk++){
      acc0 = dot2(a1h[kk], w2h[(2*j)*16+kk],   acc0);
      acc1 = dot2(a1h[kk], w2h[(2*j+1)*16+kk], acc1);
    }
    a2h[j] = pk2(fmaxf(acc0,0.f), fmaxf(acc1,0.f));
  }
  // ---- layer 3: 64 -> 32 ----
  f16x2 a3h[16];
  #pragma unroll
  for (int j=0;j<16;j++){
    float acc0 = b3L[2*j], acc1 = b3L[2*j+1];
    #pragma unroll
    for (int kk=0;kk<32;kk++){
      acc0 = dot2(a2h[kk], w3h[(2*j)*32+kk],   acc0);
      acc1 = dot2(a2h[kk], w3h[(2*j+1)*32+kk], acc1);
    }
    a3h[j] = pk2(fmaxf(acc0,0.f), fmaxf(acc1,0.f));
  }
  // ---- layer 4: 32 -> 16 (no relu) ----
  f16x2 eh4[8];
  #pragma unroll
  for (int j=0;j<8;j++){
    float acc0 = b4L[2*j], acc1 = b4L[2*j+1];
    #pragma unroll
    for (int kk=0;kk<16;kk++){
      acc0 = dot2(a3h[kk], w4h[(2*j)*16+kk],   acc0);
      acc1 = dot2(a3h[kk], w4h[(2*j+1)*16+kk], acc1);
    }
    eh4[j] = pk2(acc0, acc1);
  }
  // ---- edge head + log_softmax(4) ----
  f16x2 th[8];
  #pragma unroll
  for (int j=0;j<8;j++){
    float acc0 = eb1L[2*j], acc1 = eb1L[2*j+1];
    #pragma unroll
    for (int kk=0;kk<8;kk++){
      acc0 = dot2(eh4[kk], ew1h[(2*j)*8+kk],   acc0);
      acc1 = dot2(eh4[kk], ew1h[(2*j+1)*8+kk], acc1);
    }
    th[j] = pk2(fmaxf(acc0,0.f), fmaxf(acc1,0.f));
  }
  float y0 = eb2L[0], y1 = eb2L[1], y2 = eb2L[2], y3 = eb2L[3];
  #pragma unroll
  for (int kk=0;kk<8;kk++){
    y0 = dot2(th[kk], ew2h[0*8+kk], y0);
    y1 = dot2(th[kk], ew2h[1*8+kk], y1);
    y2 = dot2(th[kk], ew2h[2*8+kk], y2);
    y3 = dot2(th[kk], ew2h[3*8+kk], y3);
  }
  y0 = fmaxf(y0,0.f); y1 = fmaxf(y1,0.f); y2 = fmaxf(y2,0.f); y3 = fmaxf(y3,0.f);
  float m = fmaxf(fmaxf(y0,y1), fmaxf(y2,y3));
  float l = m + __logf(__expf(y0-m)+__expf(y1-m)+__expf(y2-m)+__expf(y3-m));
  float4 eo; eo.x = y0-l; eo.y = y1-l; eo.z = y2-l; eo.w = y3-l;
  ((float4*)eout)[i] = eo;

  // ---- conv2 alpha -> CSR scatter ----
  float al = hs2[s] + hd2[d];
  #pragma unroll
  for (int kk=0;kk<8;kk++) al = dot2(eh4[kk], w16h[kk], al);
  al = al > 0.f ? al : 0.2f*al;
  float ex = __expf(al);
  int pos = off[d] + atomicAdd(&cnt[d], 1);
  edata[pos] = make_float2(ex, __int_as_float(s));
}

// ---------------- kagg2: conv2 CSR reduce + fused node head ----------------
// 64 lanes/node = 16 feat x 4 k-slots; after ks-reduce every lane holds its
// feature total + full denominator; head GEMV via width-16 shuffles; lane 0
// writes log_softmax(2). Replaces kagg2+k7 and the acc round-trip.
__global__ __launch_bounds__(256,8) void kagg2(const float2* __restrict__ edata,
    const int* __restrict__ off, const u16* __restrict__ hpk,
    const float* __restrict__ c2b,
    const float* __restrict__ w1p, const float* __restrict__ b1p,
    const float* __restrict__ w2p, const float* __restrict__ b2p,
    float* __restrict__ nout, int* __restrict__ cnt)
{
  __shared__ float w1L[256], cb[16], b1L[16], w2L[32], b2L[2];
  int tid = threadIdx.x;
  w1L[tid] = w1p[tid];
  if (tid < 16){ cb[tid] = c2b[tid]; b1L[tid] = b1p[tid]; }
  if (tid < 32) w2L[tid] = w2p[tid];
  if (tid < 2)  b2L[tid] = b2p[tid];
  __syncthreads();
  int t = blockIdx.x*256 + tid;
  int n = t >> 6;
  int l = t & 63;
  if (n >= NN) return;
  int j = l & 15, ks = l >> 4;
  int beg = off[n], end = off[n+1];
  float aj = 0.f, sl = 0.f;
  for (int k = beg + ks; k < end; k += 4){
    float2 p = edata[k];
    int src = __float_as_int(p.y);
    aj += p.x * f16u(hpk[(size_t)src*16 + j]);
    sl += p.x;
  }
  aj += __shfl_xor(aj, 16, 64); aj += __shfl_xor(aj, 32, 64);
  sl += __shfl_xor(sl, 16, 64); sl += __shfl_xor(sl, 32, 64);
  float inv = 1.f/(sl + 1e-16f);
  float vj = aj*inv + cb[j];
  // node head layer 1: t_j = relu(b1[j] + sum_k v_k * w1[j*16+k])
  float tj = b1L[j];
  #pragma unroll
  for (int k=0;k<16;k++){
    float vk = __shfl(vj, k, 16);
    tj += vk * w1L[j*16 + k];
  }
  tj = fmaxf(tj, 0.f);
  // layer 2: y0/y1 = relu(b2 + sum_j t_j * w2[..])
  float p0 = tj * w2L[j];
  float p1 = tj * w2L[16 + j];
  #pragma unroll
  for (int ofs=1; ofs<16; ofs<<=1){
    p0 += __shfl_xor(p0, ofs, 64);
    p1 += __shfl_xor(p1, ofs, 64);
  }
  if (l == 0){
    float y0 = fmaxf(p0 + b2L[0], 0.f);
    float y1 = fmaxf(p1 + b2L[1], 0.f);
    float m = fmaxf(y0, y1);
    float lg = m + __logf(__expf(y0-m) + __expf(y1-m));
    float2 no; no.x = y0-lg; no.y = y1-lg;
    ((float2*)nout)[n] = no;
    cnt[n] = 0;
  }
}

extern "C" void kernel_launch(void* const* d_in, const int* in_sizes, int n_in,
                              void* d_out, int out_size, void* d_ws, size_t ws_size,
                              hipStream_t stream)
{
  const float* x  = (const float*)d_in[0];
  const int* ei   = (const int*)d_in[1];
  const float* ea = (const float*)d_in[2];
  const float* c1Wx = (const float*)d_in[3];
  const float* c1We = (const float*)d_in[4];
  const float* c1as = (const float*)d_in[5];
  const float* c1ad = (const float*)d_in[6];
  const float* c1ae = (const float*)d_in[7];
  const float* c1b  = (const float*)d_in[8];
  const float* e1w1 = (const float*)d_in[9];
  const float* e1b1 = (const float*)d_in[10];
  const float* e1w2 = (const float*)d_in[11];
  const float* e1b2 = (const float*)d_in[12];
  const float* e1w3 = (const float*)d_in[13];
  const float* e1b3 = (const float*)d_in[14];
  const float* e1w4 = (const float*)d_in[15];
  const float* e1b4 = (const float*)d_in[16];
  const float* c2Wx = (const float*)d_in[17];
  const float* c2We = (const float*)d_in[18];
  const float* c2as = (const float*)d_in[19];
  const float* c2ad = (const float*)d_in[20];
  const float* c2ae = (const float*)d_in[21];
  const float* c2b  = (const float*)d_in[22];
  const float* nlw1 = (const float*)d_in[23];
  const float* nlb1 = (const float*)d_in[24];
  const float* nlw2 = (const float*)d_in[25];
  const float* nlb2 = (const float*)d_in[26];
  const float* elw1 = (const float*)d_in[27];
  const float* elb1 = (const float*)d_in[28];
  const float* elw2 = (const float*)d_in[29];
  const float* elb2 = (const float*)d_in[30];

  float* ws = (float*)d_ws;
  const size_t N = NN;
  int* off   = (int*)ws;                     // N+8
  int* cnt   = (int*)ws + (N + 8);           // N
  int* bsum  = (int*)ws + (2*N + 8);         // 128
  int* boff  = (int*)ws + (2*N + 136);       // 128
  u32* hpk   = (u32*)(ws + 2*N + 264);       // 8N u32 (f16x2-packed h2)
  float* hs  = ws + 10*N + 264;              // N
  float* hd  = hs + N;                       // N
  float* acc4= hd + N;                       // 4N  (conv1 agg of x)
  float* s   = acc4 + 4*N;                   // N
  u32* uh    = (u32*)(s + N);                // 16N u32
  u32* vh    = uh + 16*N;                    // 16N u32
  float2* edata = (float2*)(vh + 16*N);      // NE float2

  float* nout = (float*)d_out;               // [100000, 2]
  float* eout = (float*)d_out + 200000;      // [3200000, 4]

  const int GE = (NE + 255)/256;
  const int GN = (NN + 255)/256;

  (void)hipMemsetAsync(cnt, 0, N*sizeof(int), stream);
  khist<<<GE, 256, 0, stream>>>(ei, cnt);
  kscanA<<<NB, 1024, 0, stream>>>(cnt, bsum);
  kscanB<<<1, 64, 0, stream>>>(bsum, boff, off + NN);
  kscanC<<<NB, 1024, 0, stream>>>(cnt, boff, off, acc4, s);
  k1<<<GN, 256, 0, stream>>>(x, c1Wx, c1as, c1ad, hs, hd);
  k2a<<<GE, 256, 0, stream>>>(ei, ea, c1We, c1ae, hs, hd, x, acc4, s);
  k4<<<GN, 256, 0, stream>>>(acc4, s, c1b, c1Wx, c2Wx, c2as, c2ad, e1w1, hpk, hs, hd, uh, vh);
  k5<<<GE, 256, 0, stream>>>(ei, ea, uh, vh, hs, hd,
      e1w1, e1b1, e1w2, e1b2, e1w3, e1b3, e1w4, e1b4,
      c2We, c2ae, elw1, elb1, elw2, elb2,
      off, cnt, edata, eout);
  kagg2<<<(NN*64 + 255)/256, 256, 0, stream>>>(edata, off, (const u16*)hpk,
      c2b, nlw1, nlb1, nlw2, nlb2, nout, cnt);
}

// Round 16
// 760.273 us; speedup vs baseline: 1.8047x; 1.8047x over previous
//
#include <hip/hip_runtime.h>

#define NN 100000
#define NE 3200000
#define NB 98   // ceil(NN/1024)

typedef unsigned int u32;
typedef unsigned short u16;
typedef _Float16 f16x2 __attribute__((ext_vector_type(2)));
typedef __fp16 fp16v2 __attribute__((ext_vector_type(2)));

__device__ __forceinline__ int clampi(int s){
  s = s < 0 ? 0 : s;
  return s >= NN ? NN-1 : s;
}

__device__ __forceinline__ f16x2 pk2(float x, float y){
  fp16v2 r = __builtin_amdgcn_cvt_pkrtz(x, y);
  return __builtin_bit_cast(f16x2, r);
}
__device__ __forceinline__ float dot2(f16x2 a, f16x2 b, float c){
  return __builtin_amdgcn_fdot2(a, b, c, false);
}
__device__ __forceinline__ float f16lo(u32 w){
  __fp16 h = __builtin_bit_cast(__fp16, (u16)(w & 0xffffu));
  return (float)h;
}
__device__ __forceinline__ float f16hi(u32 w){
  __fp16 h = __builtin_bit_cast(__fp16, (u16)(w >> 16));
  return (float)h;
}
__device__ __forceinline__ float f16u(u16 w){
  __fp16 h = __builtin_bit_cast(__fp16, w);
  return (float)h;
}

// dual-accumulator dot (f32, used by k4)
template<int N4>
__device__ __forceinline__ float dotl(const float* __restrict__ a, const float* w){
  float acc0 = 0.f, acc1 = 0.f;
  #pragma unroll
  for (int k = 0; k < N4; k += 2){
    float4 q0 = ((const float4*)w)[k];
    acc0 += a[4*k]*q0.x + a[4*k+1]*q0.y + a[4*k+2]*q0.z + a[4*k+3]*q0.w;
    float4 q1 = ((const float4*)w)[k+1];
    acc1 += a[4*k+4]*q1.x + a[4*k+5]*q1.y + a[4*k+6]*q1.z + a[4*k+7]*q1.w;
  }
  return acc0 + acc1;
}

// ---------------- khist: cnt[d]++ ------------------------------------------
__global__ __launch_bounds__(256,8) void khist(const int* __restrict__ ei, int* __restrict__ cnt){
  int i = blockIdx.x*256 + threadIdx.x;
  if (i >= NE) return;
  atomicAdd(&cnt[clampi(ei[NE+i])], 1);
}

// ---------------- kscanA: per-block sums of cnt -----------------------------
__global__ __launch_bounds__(1024) void kscanA(const int* __restrict__ cnt, int* __restrict__ bsum){
  __shared__ int wsum[16];
  int tid = threadIdx.x;
  int i = blockIdx.x*1024 + tid;
  int x = (i < NN) ? cnt[i] : 0;
  #pragma unroll
  for (int ofs = 1; ofs < 64; ofs <<= 1) x += __shfl_xor(x, ofs, 64);
  if ((tid & 63) == 0) wsum[tid >> 6] = x;
  __syncthreads();
  if (tid == 0){
    int t = 0;
    #pragma unroll
    for (int k = 0; k < 16; k++) t += wsum[k];
    bsum[blockIdx.x] = t;
  }
}

// ---------------- kscanB: scan the 98 block sums ----------------------------
__global__ void kscanB(const int* __restrict__ bsum, int* __restrict__ boff, int* __restrict__ offN){
  if (threadIdx.x == 0){
    int c = 0;
    for (int b = 0; b < NB; b++){ boff[b] = c; c += bsum[b]; }
    offN[0] = c;
  }
}

// ---------------- kscanC: block-local scan + offset; cnt = 0 ----------------
__global__ __launch_bounds__(1024) void kscanC(int* __restrict__ cnt, const int* __restrict__ boff,
                                               int* __restrict__ off){
  __shared__ int wsum[16];
  int tid = threadIdx.x;
  int i = blockIdx.x*1024 + tid;
  int v = (i < NN) ? cnt[i] : 0;
  int x = v;
  #pragma unroll
  for (int ofs = 1; ofs < 64; ofs <<= 1){
    int t = __shfl_up(x, ofs, 64);
    if ((tid & 63) >= ofs) x += t;
  }
  if ((tid & 63) == 63) wsum[tid >> 6] = x;
  __syncthreads();
  if (tid < 16){
    int y = wsum[tid];
    #pragma unroll
    for (int ofs = 1; ofs < 16; ofs <<= 1){
      int t = __shfl_up(y, ofs, 64);
      if (tid >= ofs) y += t;
    }
    wsum[tid] = y;
  }
  __syncthreads();
  int wb = (tid >= 64) ? wsum[(tid >> 6) - 1] : 0;
  if (i < NN){ off[i] = boff[blockIdx.x] + wb + x - v; cnt[i] = 0; }
}

// ---------------- k1: hs1 = (Wx x).a_src ; hd1 = (Wx x).a_dst ---------------
__global__ __launch_bounds__(256,4) void k1(const float* __restrict__ x,
    const float* __restrict__ Wx, const float* __restrict__ asrc, const float* __restrict__ adst,
    float* __restrict__ hs1, float* __restrict__ hd1)
{
  __shared__ float wL[64], aS[16], aD[16];
  int tid = threadIdx.x;
  if (tid < 64) wL[tid] = Wx[tid];
  if (tid < 16){ aS[tid] = asrc[tid]; aD[tid] = adst[tid]; }
  __syncthreads();
  int n = blockIdx.x*256 + tid;
  if (n >= NN) return;
  float4 xr = ((const float4*)x)[n];
  float hs=0.f, hd=0.f;
  #pragma unroll
  for (int j=0;j<16;j++){
    float h = xr.x*wL[j*4+0] + xr.y*wL[j*4+1] + xr.z*wL[j*4+2] + xr.w*wL[j*4+3];
    hs += h*aS[j]; hd += h*aD[j];
  }
  hs1[n]=hs; hd1[n]=hd;
}

// ---------------- k2a: alpha1 -> CSR scatter (r14 known-good) ---------------
// r15 lesson re-learned: 5 contended f32 atomics/edge = 795us (VALUBusy 0.4%,
// atomic serialization). CSR cursor scatter (1 int atomic + 8B store) = ~55us.
__global__ __launch_bounds__(256,8) void k2a(const int* __restrict__ ei,
    const float* __restrict__ ea, const float* __restrict__ We, const float* __restrict__ aedge,
    const float* __restrict__ hs1, const float* __restrict__ hd1,
    const int* __restrict__ off, int* __restrict__ cnt, float2* __restrict__ edata)
{
  __shared__ float w6[6];
  int tid = threadIdx.x;
  if (tid < 6){
    float acc = 0.f;
    for (int j=0;j<16;j++) acc += aedge[j] * We[j*6+tid];
    w6[tid] = acc;
  }
  __syncthreads();
  int i = blockIdx.x*256 + tid;
  if (i >= NE) return;
  int s = clampi(ei[i]);
  int d = clampi(ei[NE + i]);
  const float2* eap = (const float2*)ea + (size_t)i*3;
  float2 u0 = eap[0], u1 = eap[1], u2 = eap[2];
  float al = hs1[s] + hd1[d]
    + u0.x*w6[0] + u0.y*w6[1] + u1.x*w6[2]
    + u1.y*w6[3] + u2.x*w6[4] + u2.y*w6[5];
  al = al > 0.f ? al : 0.2f*al;
  float ex = __expf(al);
  int pos = off[d] + atomicAdd(&cnt[d], 1);
  edata[pos] = make_float2(ex, __int_as_float(s));
}

// ---------------- kaggx: conv1 agg over x (4 feat x 4 k-slots / 16 lanes) ---
__global__ __launch_bounds__(256,8) void kaggx(const float2* __restrict__ edata,
    const int* __restrict__ off, const float* __restrict__ x,
    float* __restrict__ acc4, float* __restrict__ s, int* __restrict__ cnt)
{
  int t = blockIdx.x*256 + threadIdx.x;
  int n = t >> 4;
  int j = t & 15;
  if (n >= NN) return;
  int f = j & 3, ks = j >> 2;
  int beg = off[n], end = off[n+1];
  float aj = 0.f, sl = 0.f;
  for (int k = beg + ks; k < end; k += 4){
    float2 p = edata[k];
    int src = __float_as_int(p.y);
    aj += p.x * x[(size_t)src*4 + f];
    sl += p.x;
  }
  aj += __shfl_xor(aj, 4, 64); aj += __shfl_xor(aj, 8, 64);
  sl += __shfl_xor(sl, 4, 64); sl += __shfl_xor(sl, 8, 64);
  if (ks == 0) acc4[(size_t)n*4 + f] = aj;
  if (j == 0){ s[n] = sl; cnt[n] = 0; }
}

// ---------------- k4: x1 = Wx1.(acc4/s) + b1 ; h2 ; hs2 ; hd2 ; u,v ---------
__global__ __launch_bounds__(256,2) void k4(const float* __restrict__ acc4,
    const float* __restrict__ sb, const float* __restrict__ c1b,
    const float* __restrict__ Wx1, const float* __restrict__ Wx2,
    const float* __restrict__ a2s, const float* __restrict__ a2d,
    const float* __restrict__ w1p,
    u32* __restrict__ hpk,
    float* __restrict__ hs2, float* __restrict__ hd2,
    u32* __restrict__ uh, u32* __restrict__ vh)
{
  __shared__ float wL[256], bL[16], aS[16], aD[16], w0L[64];
  __shared__ float w1sL[32*16], w1dL[32*16];
  int tid = threadIdx.x;
  wL[tid] = Wx2[tid];
  if (tid < 64) w0L[tid] = Wx1[tid];
  if (tid < 16){ bL[tid]=c1b[tid]; aS[tid]=a2s[tid]; aD[tid]=a2d[tid]; }
  for (int idx=tid; idx<512; idx+=256){
    int j=idx>>4, k=idx&15;
    w1sL[idx] = w1p[j*38+k];
    w1dL[idx] = w1p[j*38+22+k];
  }
  __syncthreads();
  int n = blockIdx.x*256 + tid;
  if (n >= NN) return;
  float inv = 1.f/(sb[n] + 1e-16f);
  float4 a4 = ((const float4*)acc4)[n];
  float m0 = a4.x*inv, m1 = a4.y*inv, m2 = a4.z*inv, m3 = a4.w*inv;
  float xv[16];
  #pragma unroll
  for (int j=0;j<16;j++)
    xv[j] = m0*w0L[j*4+0] + m1*w0L[j*4+1] + m2*w0L[j*4+2] + m3*w0L[j*4+3] + bL[j];
  float hs=0.f, hd=0.f;
  float hv[16];
  #pragma unroll
  for (int j=0;j<16;j++){
    float acc = 0.f;
    #pragma unroll
    for (int k=0;k<16;k++) acc += xv[k]*wL[j*16+k];
    hv[j] = acc; hs += acc*aS[j]; hd += acc*aD[j];
  }
  u32* hr = hpk + (size_t)n*8;
  #pragma unroll
  for (int j=0;j<8;j++) hr[j] = __builtin_bit_cast(u32, pk2(hv[2*j], hv[2*j+1]));
  hs2[n]=hs; hd2[n]=hd;
  u32* ur = uh + (size_t)n*16;
  u32* vr = vh + (size_t)n*16;
  #pragma unroll
  for (int j=0;j<16;j++){
    float u0 = dotl<4>(xv, &w1sL[(2*j)*16]);
    float u1 = dotl<4>(xv, &w1sL[(2*j+1)*16]);
    ur[j] = __builtin_bit_cast(u32, pk2(u0, u1));
    float v0 = dotl<4>(xv, &w1dL[(2*j)*16]);
    float v1 = dotl<4>(xv, &w1dL[(2*j+1)*16]);
    vr[j] = __builtin_bit_cast(u32, pk2(v0, v1));
  }
}

// ---------------- k5: edge MLP (f16 dot2) + edge head + alpha2 scatter ------
// (256,5): known-good from r13/r14 (370us, VGPR 48, no spill). UNCHANGED.
__global__ __launch_bounds__(256,5) void k5(
    const int* __restrict__ ei, const float* __restrict__ ea,
    const u32* __restrict__ uh, const u32* __restrict__ vh,
    const float* __restrict__ hs2, const float* __restrict__ hd2,
    const float* w1p, const float* b1p, const float* w2p, const float* b2p,
    const float* w3p, const float* b3p, const float* w4p, const float* b4p,
    const float* We2, const float* a2e,
    const float* ew1p, const float* eb1p, const float* ew2p, const float* eb2p,
    const int* __restrict__ off, int* __restrict__ cnt, float2* __restrict__ edata,
    float* __restrict__ eout)
{
  __shared__ __align__(16) f16x2 w1eh[32*4];  __shared__ float b1L[32];
  __shared__ __align__(16) f16x2 w2h[64*16];  __shared__ float b2L[64];
  __shared__ __align__(16) f16x2 w3h[32*32];  __shared__ float b3L[32];
  __shared__ __align__(16) f16x2 w4h[16*16];  __shared__ float b4L[16];
  __shared__ __align__(16) f16x2 ew1h[16*8];  __shared__ float eb1L[16];
  __shared__ __align__(16) f16x2 ew2h[4*8];   __shared__ float eb2L[4];
  __shared__ __align__(16) f16x2 w16h[8];
  int tid = threadIdx.x;
  if (tid < 128){
    int j=tid>>2, kk=tid&3;
    int k0=2*kk, k1=2*kk+1;
    float v0 = (k0<6) ? w1p[j*38+16+k0] : 0.f;
    float v1 = (k1<6) ? w1p[j*38+16+k1] : 0.f;
    w1eh[tid] = pk2(v0, v1);
  }
  for (int idx=tid; idx<1024; idx+=256){
    int j=idx>>4, kk=idx&15;
    w2h[idx] = pk2(w2p[j*32+2*kk], w2p[j*32+2*kk+1]);
  }
  for (int idx=tid; idx<1024; idx+=256){
    int j=idx>>5, kk=idx&31;
    w3h[idx] = pk2(w3p[j*64+2*kk], w3p[j*64+2*kk+1]);
  }
  if (tid < 256){
    int j=tid>>4, kk=tid&15;
    w4h[tid] = pk2(w4p[j*32+2*kk], w4p[j*32+2*kk+1]);
  }
  if (tid < 128){
    int j=tid>>3, kk=tid&7;
    ew1h[tid] = pk2(ew1p[j*16+2*kk], ew1p[j*16+2*kk+1]);
  }
  if (tid < 32){
    int j=tid>>3, kk=tid&7;
    ew2h[tid] = pk2(ew2p[j*16+2*kk], ew2p[j*16+2*kk+1]);
  }
  if (tid < 8){
    float s0=0.f, s1=0.f;
    for (int j=0;j<16;j++){
      s0 += a2e[j] * We2[j*16 + 2*tid];
      s1 += a2e[j] * We2[j*16 + 2*tid + 1];
    }
    w16h[tid] = pk2(s0, s1);
  }
  if (tid < 64) b2L[tid] = b2p[tid];
  if (tid < 32){ b1L[tid] = b1p[tid]; b3L[tid] = b3p[tid]; }
  if (tid < 16){ b4L[tid] = b4p[tid]; eb1L[tid] = eb1p[tid]; }
  if (tid < 4)  eb2L[tid] = eb2p[tid];
  __syncthreads();

  int i = blockIdx.x*256 + tid;
  if (i >= NE) return;
  int s = clampi(ei[i]);
  int d = clampi(ei[NE + i]);

  // ---- layer 1: a1 = relu(u[s] + v[d] + W1e.ea + b1) ----
  f16x2 a1h[16];
  {
    const float2* eap = (const float2*)ea + (size_t)i*3;
    float2 e0=eap[0], e1=eap[1], e2=eap[2];
    f16x2 eh[4];
    eh[0]=pk2(e0.x,e0.y); eh[1]=pk2(e1.x,e1.y); eh[2]=pk2(e2.x,e2.y); eh[3]=pk2(0.f,0.f);
    const uint4* up = (const uint4*)(uh + (size_t)s*16);
    const uint4* vp = (const uint4*)(vh + (size_t)d*16);
    uint4 U[4], V[4];
    #pragma unroll
    for (int q=0;q<4;q++){ U[q]=up[q]; V[q]=vp[q]; }
    u32 uw[16], vw[16];
    #pragma unroll
    for (int q=0;q<4;q++){
      uw[4*q]=U[q].x; uw[4*q+1]=U[q].y; uw[4*q+2]=U[q].z; uw[4*q+3]=U[q].w;
      vw[4*q]=V[q].x; vw[4*q+1]=V[q].y; vw[4*q+2]=V[q].z; vw[4*q+3]=V[q].w;
    }
    #pragma unroll
    for (int j=0;j<16;j++){
      float t0 = b1L[2*j]   + f16lo(uw[j]) + f16lo(vw[j]);
      float t1 = b1L[2*j+1] + f16hi(uw[j]) + f16hi(vw[j]);
      #pragma unroll
      for (int kk=0;kk<4;kk++){
        t0 = dot2(eh[kk], w1eh[(2*j)*4+kk],   t0);
        t1 = dot2(eh[kk], w1eh[(2*j+1)*4+kk], t1);
      }
      a1h[j] = pk2(fmaxf(t0,0.f), fmaxf(t1,0.f));
    }
  }
  // ---- layer 2: 32 -> 64 ----
  f16x2 a2h[32];
  #pragma unroll
  for (int j=0;j<32;j++){
    float acc0 = b2L[2*j], acc1 = b2L[2*j+1];
    #pragma unroll
    for (int kk=0;kk<16;kk++){
      acc0 = dot2(a1h[kk], w2h[(2*j)*16+kk],   acc0);
      acc1 = dot2(a1h[kk], w2h[(2*j+1)*16+kk], acc1);
    }
    a2h[j] = pk2(fmaxf(acc0,0.f), fmaxf(acc1,0.f));
  }
  // ---- layer 3: 64 -> 32 ----
  f16x2 a3h[16];
  #pragma unroll
  for (int j=0;j<16;j++){
    float acc0 = b3L[2*j], acc1 = b3L[2*j+1];
    #pragma unroll
    for (int kk=0;kk<32;kk++){
      acc0 = dot2(a2h[kk], w3h[(2*j)*32+kk],   acc0);
      acc1 = dot2(a2h[kk], w3h[(2*j+1)*32+kk], acc1);
    }
    a3h[j] = pk2(fmaxf(acc0,0.f), fmaxf(acc1,0.f));
  }
  // ---- layer 4: 32 -> 16 (no relu) ----
  f16x2 eh4[8];
  #pragma unroll
  for (int j=0;j<8;j++){
    float acc0 = b4L[2*j], acc1 = b4L[2*j+1];
    #pragma unroll
    for (int kk=0;kk<16;kk++){
      acc0 = dot2(a3h[kk], w4h[(2*j)*16+kk],   acc0);
      acc1 = dot2(a3h[kk], w4h[(2*j+1)*16+kk], acc1);
    }
    eh4[j] = pk2(acc0, acc1);
  }
  // ---- edge head + log_softmax(4) ----
  f16x2 th[8];
  #pragma unroll
  for (int j=0;j<8;j++){
    float acc0 = eb1L[2*j], acc1 = eb1L[2*j+1];
    #pragma unroll
    for (int kk=0;kk<8;kk++){
      acc0 = dot2(eh4[kk], ew1h[(2*j)*8+kk],   acc0);
      acc1 = dot2(eh4[kk], ew1h[(2*j+1)*8+kk], acc1);
    }
    th[j] = pk2(fmaxf(acc0,0.f), fmaxf(acc1,0.f));
  }
  float y0 = eb2L[0], y1 = eb2L[1], y2 = eb2L[2], y3 = eb2L[3];
  #pragma unroll
  for (int kk=0;kk<8;kk++){
    y0 = dot2(th[kk], ew2h[0*8+kk], y0);
    y1 = dot2(th[kk], ew2h[1*8+kk], y1);
    y2 = dot2(th[kk], ew2h[2*8+kk], y2);
    y3 = dot2(th[kk], ew2h[3*8+kk], y3);
  }
  y0 = fmaxf(y0,0.f); y1 = fmaxf(y1,0.f); y2 = fmaxf(y2,0.f); y3 = fmaxf(y3,0.f);
  float m = fmaxf(fmaxf(y0,y1), fmaxf(y2,y3));
  float l = m + __logf(__expf(y0-m)+__expf(y1-m)+__expf(y2-m)+__expf(y3-m));
  float4 eo; eo.x = y0-l; eo.y = y1-l; eo.z = y2-l; eo.w = y3-l;
  ((float4*)eout)[i] = eo;

  // ---- conv2 alpha -> CSR scatter ----
  float al = hs2[s] + hd2[d];
  #pragma unroll
  for (int kk=0;kk<8;kk++) al = dot2(eh4[kk], w16h[kk], al);
  al = al > 0.f ? al : 0.2f*al;
  float ex = __expf(al);
  int pos = off[d] + atomicAdd(&cnt[d], 1);
  edata[pos] = make_float2(ex, __int_as_float(s));
}

// ---------------- kagg2: conv2 CSR reduce + fused node head ----------------
__global__ __launch_bounds__(256,8) void kagg2(const float2* __restrict__ edata,
    const int* __restrict__ off, const u16* __restrict__ hpk,
    const float* __restrict__ c2b,
    const float* __restrict__ w1p, const float* __restrict__ b1p,
    const float* __restrict__ w2p, const float* __restrict__ b2p,
    float* __restrict__ nout, int* __restrict__ cnt)
{
  __shared__ float w1L[256], cb[16], b1L[16], w2L[32], b2L[2];
  int tid = threadIdx.x;
  w1L[tid] = w1p[tid];
  if (tid < 16){ cb[tid] = c2b[tid]; b1L[tid] = b1p[tid]; }
  if (tid < 32) w2L[tid] = w2p[tid];
  if (tid < 2)  b2L[tid] = b2p[tid];
  __syncthreads();
  int t = blockIdx.x*256 + tid;
  int n = t >> 6;
  int l = t & 63;
  if (n >= NN) return;
  int j = l & 15, ks = l >> 4;
  int beg = off[n], end = off[n+1];
  float aj = 0.f, sl = 0.f;
  for (int k = beg + ks; k < end; k += 4){
    float2 p = edata[k];
    int src = __float_as_int(p.y);
    aj += p.x * f16u(hpk[(size_t)src*16 + j]);
    sl += p.x;
  }
  aj += __shfl_xor(aj, 16, 64); aj += __shfl_xor(aj, 32, 64);
  sl += __shfl_xor(sl, 16, 64); sl += __shfl_xor(sl, 32, 64);
  float inv = 1.f/(sl + 1e-16f);
  float vj = aj*inv + cb[j];
  float tj = b1L[j];
  #pragma unroll
  for (int k=0;k<16;k++){
    float vk = __shfl(vj, k, 16);
    tj += vk * w1L[j*16 + k];
  }
  tj = fmaxf(tj, 0.f);
  float p0 = tj * w2L[j];
  float p1 = tj * w2L[16 + j];
  #pragma unroll
  for (int ofs=1; ofs<16; ofs<<=1){
    p0 += __shfl_xor(p0, ofs, 64);
    p1 += __shfl_xor(p1, ofs, 64);
  }
  if (l == 0){
    float y0 = fmaxf(p0 + b2L[0], 0.f);
    float y1 = fmaxf(p1 + b2L[1], 0.f);
    float m = fmaxf(y0, y1);
    float lg = m + __logf(__expf(y0-m) + __expf(y1-m));
    float2 no; no.x = y0-lg; no.y = y1-lg;
    ((float2*)nout)[n] = no;
    cnt[n] = 0;
  }
}

extern "C" void kernel_launch(void* const* d_in, const int* in_sizes, int n_in,
                              void* d_out, int out_size, void* d_ws, size_t ws_size,
                              hipStream_t stream)
{
  const float* x  = (const float*)d_in[0];
  const int* ei   = (const int*)d_in[1];
  const float* ea = (const float*)d_in[2];
  const float* c1Wx = (const float*)d_in[3];
  const float* c1We = (const float*)d_in[4];
  const float* c1as = (const float*)d_in[5];
  const float* c1ad = (const float*)d_in[6];
  const float* c1ae = (const float*)d_in[7];
  const float* c1b  = (const float*)d_in[8];
  const float* e1w1 = (const float*)d_in[9];
  const float* e1b1 = (const float*)d_in[10];
  const float* e1w2 = (const float*)d_in[11];
  const float* e1b2 = (const float*)d_in[12];
  const float* e1w3 = (const float*)d_in[13];
  const float* e1b3 = (const float*)d_in[14];
  const float* e1w4 = (const float*)d_in[15];
  const float* e1b4 = (const float*)d_in[16];
  const float* c2Wx = (const float*)d_in[17];
  const float* c2We = (const float*)d_in[18];
  const float* c2as = (const float*)d_in[19];
  const float* c2ad = (const float*)d_in[20];
  const float* c2ae = (const float*)d_in[21];
  const float* c2b  = (const float*)d_in[22];
  const float* nlw1 = (const float*)d_in[23];
  const float* nlb1 = (const float*)d_in[24];
  const float* nlw2 = (const float*)d_in[25];
  const float* nlb2 = (const float*)d_in[26];
  const float* elw1 = (const float*)d_in[27];
  const float* elb1 = (const float*)d_in[28];
  const float* elw2 = (const float*)d_in[29];
  const float* elb2 = (const float*)d_in[30];

  float* ws = (float*)d_ws;
  const size_t N = NN;
  int* off   = (int*)ws;                     // N+8
  int* cnt   = (int*)ws + (N + 8);           // N
  int* bsum  = (int*)ws + (2*N + 8);         // 128
  int* boff  = (int*)ws + (2*N + 136);       // 128
  u32* hpk   = (u32*)(ws + 2*N + 264);       // 8N u32 (f16x2-packed h2)
  float* hs  = ws + 10*N + 264;              // N
  float* hd  = hs + N;                       // N
  float* acc4= hd + N;                       // 4N  (conv1 agg of x)
  float* s   = acc4 + 4*N;                   // N
  u32* uh    = (u32*)(s + N);                // 16N u32
  u32* vh    = uh + 16*N;                    // 16N u32
  float2* edata = (float2*)(vh + 16*N);      // NE float2

  float* nout = (float*)d_out;               // [100000, 2]
  float* eout = (float*)d_out + 200000;      // [3200000, 4]

  const int GE = (NE + 255)/256;
  const int GN = (NN + 255)/256;

  (void)hipMemsetAsync(cnt, 0, N*sizeof(int), stream);
  khist<<<GE, 256, 0, stream>>>(ei, cnt);
  kscanA<<<NB, 1024, 0, stream>>>(cnt, bsum);
  kscanB<<<1, 64, 0, stream>>>(bsum, boff, off + NN);
  kscanC<<<NB, 1024, 0, stream>>>(cnt, boff, off);
  k1<<<GN, 256, 0, stream>>>(x, c1Wx, c1as, c1ad, hs, hd);
  k2a<<<GE, 256, 0, stream>>>(ei, ea, c1We, c1ae, hs, hd, off, cnt, edata);
  kaggx<<<(NN*16 + 255)/256, 256, 0, stream>>>(edata, off, x, acc4, s, cnt);
  k4<<<GN, 256, 0, stream>>>(acc4, s, c1b, c1Wx, c2Wx, c2as, c2ad, e1w1, hpk, hs, hd, uh, vh);
  k5<<<GE, 256, 0, stream>>>(ei, ea, uh, vh, hs, hd,
      e1w1, e1b1, e1w2, e1b2, e1w3, e1b3, e1w4, e1b4,
      c2We, c2ae, elw1, elb1, elw2, elb2,
      off, cnt, edata, eout);
  kagg2<<<(NN*64 + 255)/256, 256, 0, stream>>>(edata, off, (const u16*)hpk,
      c2b, nlw1, nlb1, nlw2, nlb2, nout, cnt);
}